// Round 1
// 156.584 us; speedup vs baseline: 1.0135x; 1.0135x over previous
//
#include <hip/hip_runtime.h>
#include <math.h>

#define NB    128
#define NG    52
#define NGG   2704          // NG*NG
#define NA    3
#define NCLS  15
#define NCH   20
#define NQ    8112          // NA*NGG
#define TOTAL 1038336       // NB*NQ
#define BLK   256
#define NBLK  (TOTAL/BLK)   // 4056 (exact)
#define FPB   (BLK*NCH)     // 5120 output floats per block (20.5 KB LDS -> 7 blocks/CU)
#define NQUAD ((FPB-4)/4)   // 1279 aligned float4 stores per block

typedef float f4 __attribute__((ext_vector_type(4)));

// ---------------- main kernel: transform + noobj BCE + folded obj corrections
__global__ __launch_bounds__(BLK) void main_kernel(const float* __restrict__ x,
                                                   const float* __restrict__ labels,
                                                   float* __restrict__ out,
                                                   float* __restrict__ partials) {
    __shared__ __align__(16) float sm[FPB];   // block's 5120 out floats, shifted by -3
    __shared__ float wred[BLK/64];

    int t = threadIdx.x;
    int cell = blockIdx.x * BLK + t;          // one cell per thread
    int b  = cell / NQ;
    int r  = cell - b * NQ;
    int a  = r / NGG;
    int ji = r - a * NGG;

    const float* __restrict__ xp = x + ((size_t)(b*60 + a*20)) * NGG + ji;
    float z[NCH];
    #pragma unroll
    for (int c = 0; c < NCH; c++) z[c] = xp[c * NGG];

    float v[NCH];
    float conf = 1.0f / (1.0f + expf(-z[4]));
    v[0] = 8.0f / (1.0f + expf(-z[0]));
    v[1] = 8.0f / (1.0f + expf(-z[1]));
    v[2] = 8.0f * z[2];
    v[3] = 8.0f * z[3];
    v[4] = conf;
    float m = z[5];
    #pragma unroll
    for (int c = 6; c < NCH; c++) m = fmaxf(m, z[c]);
    float s = 0.0f;
    #pragma unroll
    for (int c = 0; c < NCLS; c++) { v[5+c] = expf(z[5+c] - m); s += v[5+c]; }
    float inv = 1.0f / s;
    #pragma unroll
    for (int c = 0; c < NCLS; c++) v[5+c] *= inv;

    // ---- per-batch target logic (folded from old finish_kernel) ----
    float gx = labels[b*5+0] * (float)NG;
    float gy = labels[b*5+1] * (float)NG;
    float gw = labels[b*5+2] * (float)NG;
    float gh = labels[b*5+3] * (float)NG;
    int  gcls = (int)labels[b*5+4];
    int gi = (int)gx, gj = (int)gy;
    float gwgh = gw * gh;
    float i0 = fminf(12.0f,   gw) * fminf(28.75f,  gh);
    float i1 = fminf(9.875f,  gw) * fminf(23.25f,  gh);
    float i2 = fminf(10.125f, gw) * fminf(16.625f, gh);
    float iou0 = i0 / (345.0f      + 1e-16f + gwgh - i0);   // 12*28.75
    float iou1 = i1 / (229.59375f  + 1e-16f + gwgh - i1);   // 9.875*23.25
    float iou2 = i2 / (168.328125f + 1e-16f + gwgh - i2);   // 10.125*16.625
    int best = 0; float bv = iou0;
    if (iou1 > bv) { best = 1; bv = iou1; }
    if (iou2 > bv) { best = 2; bv = iou2; }
    float ioua = (a == 0) ? iou0 : ((a == 1) ? iou1 : iou2);
    bool at_t   = (ji == gj * NG + gi);
    bool isbest = (a == best);

    float tsum = 0.0f;
    // noobj BCE term (x100), skipped entirely where reference zeroes the mask
    if (!(at_t && (isbest || ioua > 0.5f)))
        tsum = -100.0f * fmaxf(logf(1.0f - conf), -100.0f);
    // obj terms at the best-anchor target cell
    if (at_t && isbest) {
        tsum += -fmaxf(logf(conf), -100.0f);              // conf BCE, t=1
        float txv = gx - (float)gi;
        float tyv = gy - (float)gj;
        float abw = (best == 0) ? 12.0f  : ((best == 1) ? 9.875f : 10.125f);
        float abh = (best == 0) ? 28.75f : ((best == 1) ? 23.25f : 16.625f);
        float twv = logf(gw / abw + 1e-16f);
        float thv = logf(gh / abh + 1e-16f);
        tsum += fabsf(v[0]*0.125f - txv) + fabsf(v[1]*0.125f - tyv)
              + fabsf(v[2]*0.125f - twv) + fabsf(v[3]*0.125f - thv);
        #pragma unroll
        for (int c = 0; c < NCLS; c++) {
            float p = v[5+c];
            tsum += (c == gcls) ? -fmaxf(logf(p),        -100.0f)
                                : -fmaxf(logf(1.0f - p), -100.0f);
        }
    }

    // shifted LDS layout for aligned float4 stores
    int base = t * NCH - 3;
    #pragma unroll
    for (int c = 0; c < NCH; c++) {
        int L = base + c;
        if (L < 0) L += FPB;                   // only t==0, c<3
        sm[L] = v[c];
    }

    // wave reduce loss partial
    #pragma unroll
    for (int off = 32; off > 0; off >>= 1) tsum += __shfl_down(tsum, off, 64);
    if ((t & 63) == 0) wred[t >> 6] = tsum;

    __syncthreads();

    // coalesced nontemporal float4 stores of the block's contiguous out region
    size_t gbase = (size_t)blockIdx.x * FPB;   // out[0] is loss; tensor starts at out+1
    f4* __restrict__ op = (f4*)(out + gbase + 4);
    const f4* __restrict__ sp = (const f4*)sm;
    #pragma unroll
    for (int k = 0; k < 5; k++) {
        int q = k * BLK + t;
        if (q < NQUAD) __builtin_nontemporal_store(sp[q], &op[q]);
    }
    if (t == 0) {
        out[gbase + 1]   = sm[FPB - 3];        // leading 3 floats
        out[gbase + 2]   = sm[FPB - 2];
        out[gbase + 3]   = sm[FPB - 1];
        out[gbase + FPB] = sm[FPB - 4];        // trailing scalar
        partials[blockIdx.x] = wred[0] + wred[1] + wred[2] + wred[3];
    }
}

// ---------------- finish: tiny deterministic reduction of block partials ----
__global__ void finish_kernel(const float* __restrict__ partials,
                              float* __restrict__ out) {
    int t = threadIdx.x;   // 256 threads
    float s = 0.0f;
    for (int q = t; q < NBLK; q += 256) s += partials[q];
    __shared__ float red[256];
    red[t] = s;
    __syncthreads();
    for (int k = 128; k > 0; k >>= 1) {
        if (t < k) red[t] += red[t + k];
        __syncthreads();
    }
    if (t == 0) out[0] = red[0];
}

extern "C" void kernel_launch(void* const* d_in, const int* in_sizes, int n_in,
                              void* d_out, int out_size, void* d_ws, size_t ws_size,
                              hipStream_t stream) {
    const float* x      = (const float*)d_in[0];
    const float* labels = (const float*)d_in[1];
    float* out = (float*)d_out;
    float* ws  = (float*)d_ws;

    hipLaunchKernelGGL(main_kernel,   dim3(NBLK), dim3(BLK), 0, stream, x, labels, out, ws);
    hipLaunchKernelGGL(finish_kernel, dim3(1),    dim3(256), 0, stream, ws, out);
}